// Round 1
// baseline (6545.442 us; speedup 1.0000x reference)
//
#include <hip/hip_runtime.h>

#define E_N 200000
#define M_N 3200000

// ---------------------------------------------------------------------------
// Kernel 1: q/k/v = x @ W{q,k,v} + b   (x: E x 64, W: 64 x 64)
// One wave per 2 rows; lane j owns output column j. W matrices staged in LDS.
// ---------------------------------------------------------------------------
__global__ __launch_bounds__(256) void qkv_kernel(
    const float* __restrict__ x,
    const float* __restrict__ Wq, const float* __restrict__ bq,
    const float* __restrict__ Wk, const float* __restrict__ bk,
    const float* __restrict__ Wv, const float* __restrict__ bv,
    float* __restrict__ q, float* __restrict__ k, float* __restrict__ v)
{
    __shared__ float sWq[4096], sWk[4096], sWv[4096];
    __shared__ float sb[192];
    for (int i = threadIdx.x; i < 4096; i += 256) {
        sWq[i] = Wq[i]; sWk[i] = Wk[i]; sWv[i] = Wv[i];
    }
    if (threadIdx.x < 64)       sb[threadIdx.x]       = bq[threadIdx.x];
    else if (threadIdx.x < 128) sb[threadIdx.x]       = bk[threadIdx.x - 64];
    else if (threadIdx.x < 192) sb[threadIdx.x]       = bv[threadIdx.x - 128];
    __syncthreads();

    const int wid  = threadIdx.x >> 6;
    const int lane = threadIdx.x & 63;

    // each block-iteration: 4 waves x 2 rows = 8 rows
    for (int r0 = blockIdx.x * 8; r0 < E_N; r0 += gridDim.x * 8) {
        int ra = r0 + wid * 2;
        int rb = ra + 1;
        bool va = ra < E_N, vb = rb < E_N;
        float xa = va ? x[(long long)ra * 64 + lane] : 0.0f;
        float xb = vb ? x[(long long)rb * 64 + lane] : 0.0f;

        float aq0 = sb[lane], ak0 = sb[64 + lane], av0 = sb[128 + lane];
        float aq1 = aq0, ak1 = ak0, av1 = av0;
        #pragma unroll
        for (int i = 0; i < 64; i++) {
            float xi0 = __shfl(xa, i, 64);
            float xi1 = __shfl(xb, i, 64);
            float wq = sWq[i * 64 + lane];
            float wk = sWk[i * 64 + lane];
            float wv = sWv[i * 64 + lane];
            aq0 += xi0 * wq;  aq1 += xi1 * wq;
            ak0 += xi0 * wk;  ak1 += xi1 * wk;
            av0 += xi0 * wv;  av1 += xi1 * wv;
        }
        if (va) {
            q[(long long)ra * 64 + lane] = aq0;
            k[(long long)ra * 64 + lane] = ak0;
            v[(long long)ra * 64 + lane] = av0;
        }
        if (vb) {
            q[(long long)rb * 64 + lane] = aq1;
            k[(long long)rb * 64 + lane] = ak1;
            v[(long long)rb * 64 + lane] = av1;
        }
    }
}

// ---------------------------------------------------------------------------
// Kernel 2: per (pair, head) thread. logit = scale*q[dst,h]·k[src,h] + bias;
// w = exp(logit) (no max-subtract: logits are O(1), exp cancels in the ratio).
// Accumulate w into seg_sum[dst,h] and w*v[src,h,:] into out_acc[dst,:].
// 8 consecutive threads = 1 pair -> the 8 lanes cover one full 256B row.
// ---------------------------------------------------------------------------
__global__ __launch_bounds__(256) void pair_kernel(
    const int*   __restrict__ e2e,
    const float* __restrict__ bias,
    const float* __restrict__ q, const float* __restrict__ k,
    const float* __restrict__ v,
    float* __restrict__ segsum, float* __restrict__ outacc)
{
    long long tid = (long long)blockIdx.x * 256 + threadIdx.x;
    if (tid >= (long long)M_N * 8) return;
    int m = (int)(tid >> 3);
    int h = (int)(tid & 7);

    int src = e2e[m];
    int dst = e2e[M_N + m];

    const float4* qp = (const float4*)(q + (long long)dst * 64 + h * 8);
    const float4* kp = (const float4*)(k + (long long)src * 64 + h * 8);
    float4 q0 = qp[0], q1 = qp[1];
    float4 k0 = kp[0], k1 = kp[1];
    float dot = q0.x * k0.x + q0.y * k0.y + q0.z * k0.z + q0.w * k0.w
              + q1.x * k1.x + q1.y * k1.y + q1.z * k1.z + q1.w * k1.w;

    float logit = dot * 0.35355339059327373f + bias[(long long)m * 8 + h];
    float w = __expf(logit);

    unsafeAtomicAdd(&segsum[(long long)dst * 8 + h], w);

    const float4* vp = (const float4*)(v + (long long)src * 64 + h * 8);
    float4 v0 = vp[0], v1 = vp[1];
    float* op = outacc + (long long)dst * 64 + h * 8;
    unsafeAtomicAdd(op + 0, w * v0.x);
    unsafeAtomicAdd(op + 1, w * v0.y);
    unsafeAtomicAdd(op + 2, w * v0.z);
    unsafeAtomicAdd(op + 3, w * v0.w);
    unsafeAtomicAdd(op + 4, w * v1.x);
    unsafeAtomicAdd(op + 5, w * v1.y);
    unsafeAtomicAdd(op + 6, w * v1.z);
    unsafeAtomicAdd(op + 7, w * v1.w);
}

// ---------------------------------------------------------------------------
// Kernel 3: per edge: normalize by seg_sum, then out = msg @ Wo + bo.
// One wave per edge, in-place on d_out (row read fully before written).
// ---------------------------------------------------------------------------
__global__ __launch_bounds__(256) void out_kernel(
    const float* __restrict__ Wo, const float* __restrict__ bo,
    const float* __restrict__ segsum, float* __restrict__ out)
{
    __shared__ float sWo[4096];
    __shared__ float sbo[64];
    for (int i = threadIdx.x; i < 4096; i += 256) sWo[i] = Wo[i];
    if (threadIdx.x < 64) sbo[threadIdx.x] = bo[threadIdx.x];
    __syncthreads();

    const int wid  = threadIdx.x >> 6;
    const int lane = threadIdx.x & 63;

    for (int e0 = blockIdx.x * 4; e0 < E_N; e0 += gridDim.x * 4) {
        int e = e0 + wid;
        if (e >= E_N) continue;
        float acc = out[(long long)e * 64 + lane];
        float s   = segsum[(long long)e * 8 + (lane >> 3)];
        float msg = acc / (s + 1e-16f);
        float o = sbo[lane];
        #pragma unroll
        for (int i = 0; i < 64; i++) {
            float mi = __shfl(msg, i, 64);
            o += mi * sWo[i * 64 + lane];
        }
        out[(long long)e * 64 + lane] = o;
    }
}

extern "C" void kernel_launch(void* const* d_in, const int* in_sizes, int n_in,
                              void* d_out, int out_size, void* d_ws, size_t ws_size,
                              hipStream_t stream) {
    const float* x    = (const float*)d_in[0];
    const int*   e2e  = (const int*)  d_in[1];
    const float* bias = (const float*)d_in[2];
    const float* Wq   = (const float*)d_in[3];
    const float* bq   = (const float*)d_in[4];
    const float* Wk   = (const float*)d_in[5];
    const float* bk   = (const float*)d_in[6];
    const float* Wv   = (const float*)d_in[7];
    const float* bv   = (const float*)d_in[8];
    const float* Wo   = (const float*)d_in[9];
    const float* bo   = (const float*)d_in[10];
    float* out = (float*)d_out;

    // workspace layout: q | k | v | segsum  (all fp32)
    float* q      = (float*)d_ws;
    float* k      = q + (long long)E_N * 64;
    float* v      = k + (long long)E_N * 64;
    float* segsum = v + (long long)E_N * 64;

    hipMemsetAsync(segsum, 0, (size_t)E_N * 8 * sizeof(float), stream);
    hipMemsetAsync(out,    0, (size_t)E_N * 64 * sizeof(float), stream);

    qkv_kernel<<<768, 256, 0, stream>>>(x, Wq, bq, Wk, bk, Wv, bv, q, k, v);

    long long nthreads = (long long)M_N * 8;
    int nblocks = (int)((nthreads + 255) / 256);   // 100000
    pair_kernel<<<nblocks, 256, 0, stream>>>(e2e, bias, q, k, v, segsum, out);

    out_kernel<<<1024, 256, 0, stream>>>(Wo, bo, segsum, out);
}

// Round 2
// 1949.427 us; speedup vs baseline: 3.3576x; 3.3576x over previous
//
#include <hip/hip_runtime.h>

#define E_N 200000
#define M_N 3200000
#define SCAN_CHUNK 2048
#define NB1 98          // ceil(E_N / SCAN_CHUNK)

// ---------------------------------------------------------------------------
// k/v = x @ W{k,v} + b   (x: E x 64). One wave per 2 rows, W staged in LDS.
// ---------------------------------------------------------------------------
__global__ __launch_bounds__(256) void kv_kernel(
    const float* __restrict__ x,
    const float* __restrict__ Wk, const float* __restrict__ bk,
    const float* __restrict__ Wv, const float* __restrict__ bv,
    float* __restrict__ k, float* __restrict__ v)
{
    __shared__ float sWk[4096], sWv[4096];
    __shared__ float sb[128];
    for (int i = threadIdx.x; i < 4096; i += 256) {
        sWk[i] = Wk[i]; sWv[i] = Wv[i];
    }
    if (threadIdx.x < 64)       sb[threadIdx.x] = bk[threadIdx.x];
    else if (threadIdx.x < 128) sb[threadIdx.x] = bv[threadIdx.x - 64];
    __syncthreads();

    const int wid  = threadIdx.x >> 6;
    const int lane = threadIdx.x & 63;

    for (int r0 = blockIdx.x * 8; r0 < E_N; r0 += gridDim.x * 8) {
        int ra = r0 + wid * 2;
        int rb = ra + 1;
        bool va = ra < E_N, vb = rb < E_N;
        float xa = va ? x[(long long)ra * 64 + lane] : 0.0f;
        float xb = vb ? x[(long long)rb * 64 + lane] : 0.0f;

        float ak0 = sb[lane], av0 = sb[64 + lane];
        float ak1 = ak0, av1 = av0;
        #pragma unroll
        for (int i = 0; i < 64; i++) {
            float xi0 = __shfl(xa, i, 64);
            float xi1 = __shfl(xb, i, 64);
            float wk = sWk[i * 64 + lane];
            float wv = sWv[i * 64 + lane];
            ak0 += xi0 * wk;  ak1 += xi1 * wk;
            av0 += xi0 * wv;  av1 += xi1 * wv;
        }
        if (va) {
            k[(long long)ra * 64 + lane] = ak0;
            v[(long long)ra * 64 + lane] = av0;
        }
        if (vb) {
            k[(long long)rb * 64 + lane] = ak1;
            v[(long long)rb * 64 + lane] = av1;
        }
    }
}

// ---------------------------------------------------------------------------
// Counting sort of pairs by dst: histogram -> 3-kernel exclusive scan -> scatter
// ---------------------------------------------------------------------------
__global__ __launch_bounds__(256) void hist_kernel(
    const int* __restrict__ e2e, int* __restrict__ counts)
{
    int m = blockIdx.x * 256 + threadIdx.x;
    if (m < M_N) atomicAdd(&counts[e2e[M_N + m]], 1);
}

// scan1: per-block (2048 elems) exclusive scan into cursor; block totals out
__global__ __launch_bounds__(256) void scan1_kernel(
    const int* __restrict__ counts, int* __restrict__ cursor,
    int* __restrict__ blocksums)
{
    __shared__ int s[256];
    const int t = threadIdx.x;
    const int base = blockIdx.x * SCAN_CHUNK + t * 8;

    int vals[8];
    int tot = 0;
    #pragma unroll
    for (int j = 0; j < 8; j++) {
        int idx = base + j;
        vals[j] = (idx < E_N) ? counts[idx] : 0;
        tot += vals[j];
    }
    s[t] = tot;
    __syncthreads();
    for (int off = 1; off < 256; off <<= 1) {
        int add = (t >= off) ? s[t - off] : 0;
        __syncthreads();
        s[t] += add;
        __syncthreads();
    }
    int excl = (t == 0) ? 0 : s[t - 1];
    if (t == 255) blocksums[blockIdx.x] = s[255];

    int run = excl;
    #pragma unroll
    for (int j = 0; j < 8; j++) {
        int idx = base + j;
        if (idx < E_N) cursor[idx] = run;
        run += vals[j];
    }
}

// scan2: single block scans the NB1 block totals -> blockoff
__global__ __launch_bounds__(128) void scan2_kernel(
    const int* __restrict__ blocksums, int* __restrict__ blockoff)
{
    __shared__ int s[128];
    const int t = threadIdx.x;
    s[t] = (t < NB1) ? blocksums[t] : 0;
    __syncthreads();
    for (int off = 1; off < 128; off <<= 1) {
        int add = (t >= off) ? s[t - off] : 0;
        __syncthreads();
        s[t] += add;
        __syncthreads();
    }
    if (t < NB1) blockoff[t] = (t == 0) ? 0 : s[t - 1];
}

// scan3: add block offsets
__global__ __launch_bounds__(256) void scan3_kernel(
    int* __restrict__ cursor, const int* __restrict__ blockoff)
{
    int i = blockIdx.x * 256 + threadIdx.x;
    if (i < E_N) cursor[i] += blockoff[i >> 11];
}

// scatter: sorted[pos] = (src, m); cursor[dst] advances from start to end
__global__ __launch_bounds__(256) void scatter_kernel(
    const int* __restrict__ e2e, int* __restrict__ cursor,
    int2* __restrict__ sorted)
{
    int m = blockIdx.x * 256 + threadIdx.x;
    if (m < M_N) {
        int src = e2e[m];
        int dst = e2e[M_N + m];
        int pos = atomicAdd(&cursor[dst], 1);
        sorted[pos] = make_int2(src, m);
    }
}

// ---------------------------------------------------------------------------
// aggregate: one wave per dst edge. Computes q row on the fly (Wq in LDS),
// then loops the dst's pairs: dot(q,k[src]) via 3 shuffles, w=exp(.+bias),
// accumulate w*v[src] and w in registers; write normalized msg. NO atomics.
// Lane layout: lane = h*8+d.
// ---------------------------------------------------------------------------
__global__ __launch_bounds__(256) void aggregate_kernel(
    const float* __restrict__ x,
    const float* __restrict__ Wq, const float* __restrict__ bq,
    const float* __restrict__ k, const float* __restrict__ v,
    const float* __restrict__ bias,
    const int* __restrict__ counts, const int* __restrict__ cursor,
    const int2* __restrict__ sorted,
    float* __restrict__ msg)
{
    __shared__ float sWq[4096];
    __shared__ float sbq[64];
    for (int i = threadIdx.x; i < 4096; i += 256) sWq[i] = Wq[i];
    if (threadIdx.x < 64) sbq[threadIdx.x] = bq[threadIdx.x];
    __syncthreads();

    const int wid  = threadIdx.x >> 6;
    const int lane = threadIdx.x & 63;
    const int h    = lane >> 3;

    for (int e = blockIdx.x * 4 + wid; e < E_N; e += gridDim.x * 4) {
        // q[e][lane] = bq[lane] + sum_i x[e][i] * Wq[i][lane]
        float xv = x[(long long)e * 64 + lane];
        float qv = sbq[lane];
        #pragma unroll
        for (int i = 0; i < 64; i++) {
            qv += __shfl(xv, i, 64) * sWq[i * 64 + lane];
        }

        int end   = cursor[e];          // after scatter, cursor[e] == seg end
        int cnt   = counts[e];
        int start = end - cnt;

        float acc = 0.0f, wsum = 0.0f;
        for (int i = start; i < end; i++) {
            int2 p = sorted[i];         // (src, m)
            float kv = k[(long long)p.x * 64 + lane];
            float vv = v[(long long)p.x * 64 + lane];
            float prod = qv * kv;
            prod += __shfl_xor(prod, 1);
            prod += __shfl_xor(prod, 2);
            prod += __shfl_xor(prod, 4);   // dot over the 8 lanes of head h
            float w = __expf(prod * 0.35355339059327373f
                             + bias[(long long)p.y * 8 + h]);
            acc  += w * vv;
            wsum += w;
        }
        msg[(long long)e * 64 + lane] = acc / (wsum + 1e-16f);
    }
}

// ---------------------------------------------------------------------------
// out = msg @ Wo + bo, in-place on d_out (row fully read before written)
// ---------------------------------------------------------------------------
__global__ __launch_bounds__(256) void out_kernel(
    const float* __restrict__ Wo, const float* __restrict__ bo,
    float* __restrict__ out)
{
    __shared__ float sWo[4096];
    __shared__ float sbo[64];
    for (int i = threadIdx.x; i < 4096; i += 256) sWo[i] = Wo[i];
    if (threadIdx.x < 64) sbo[threadIdx.x] = bo[threadIdx.x];
    __syncthreads();

    const int wid  = threadIdx.x >> 6;
    const int lane = threadIdx.x & 63;

    for (int e = blockIdx.x * 4 + wid; e < E_N; e += gridDim.x * 4) {
        float m = out[(long long)e * 64 + lane];
        float o = sbo[lane];
        #pragma unroll
        for (int i = 0; i < 64; i++) {
            o += __shfl(m, i, 64) * sWo[i * 64 + lane];
        }
        out[(long long)e * 64 + lane] = o;
    }
}

extern "C" void kernel_launch(void* const* d_in, const int* in_sizes, int n_in,
                              void* d_out, int out_size, void* d_ws, size_t ws_size,
                              hipStream_t stream) {
    const float* x    = (const float*)d_in[0];
    const int*   e2e  = (const int*)  d_in[1];
    const float* bias = (const float*)d_in[2];
    const float* Wq   = (const float*)d_in[3];
    const float* bq   = (const float*)d_in[4];
    const float* Wk   = (const float*)d_in[5];
    const float* bk   = (const float*)d_in[6];
    const float* Wv   = (const float*)d_in[7];
    const float* bv   = (const float*)d_in[8];
    const float* Wo   = (const float*)d_in[9];
    const float* bo   = (const float*)d_in[10];
    float* out = (float*)d_out;

    // ws layout (floats/ints, all 4B; sorted is 8B-aligned by construction):
    // k[12.8M] | v[12.8M] | counts[200k] | cursor[200k] | bsum[128] | boff[128] | sorted[3.2M int2]
    float* k        = (float*)d_ws;
    float* v        = k + (long long)E_N * 64;
    int*   counts   = (int*)(v + (long long)E_N * 64);
    int*   cursor   = counts + E_N;
    int*   bsum     = cursor + E_N;
    int*   boff     = bsum + 128;
    int2*  sorted   = (int2*)(boff + 128);

    hipMemsetAsync(counts, 0, (size_t)E_N * sizeof(int), stream);

    kv_kernel<<<768, 256, 0, stream>>>(x, Wk, bk, Wv, bv, k, v);

    int mb = (M_N + 255) / 256;   // 12500
    hist_kernel<<<mb, 256, 0, stream>>>(e2e, counts);
    scan1_kernel<<<NB1, 256, 0, stream>>>(counts, cursor, bsum);
    scan2_kernel<<<1, 128, 0, stream>>>(bsum, boff);
    scan3_kernel<<<(E_N + 255) / 256, 256, 0, stream>>>(cursor, boff);
    scatter_kernel<<<mb, 256, 0, stream>>>(e2e, cursor, sorted);

    aggregate_kernel<<<4096, 256, 0, stream>>>(x, Wq, bq, k, v, bias,
                                               counts, cursor, sorted, out);

    out_kernel<<<1024, 256, 0, stream>>>(Wo, bo, out);
}

// Round 3
// 1284.354 us; speedup vs baseline: 5.0963x; 1.5178x over previous
//
#include <hip/hip_runtime.h>

#define E_N 200000
#define M_N 3200000
#define SCAN_CHUNK 2048
#define NB1 98          // ceil(E_N / SCAN_CHUNK)

// ---------------------------------------------------------------------------
// q/k/v = x @ W{q,k,v} + b. q goes to d_out (read back by aggregate, then
// overwritten in-place by msg). One wave per 2 rows, W staged in LDS.
// ---------------------------------------------------------------------------
__global__ __launch_bounds__(256) void qkv_kernel(
    const float* __restrict__ x,
    const float* __restrict__ Wq, const float* __restrict__ bq,
    const float* __restrict__ Wk, const float* __restrict__ bk,
    const float* __restrict__ Wv, const float* __restrict__ bv,
    float* __restrict__ q, float* __restrict__ k, float* __restrict__ v)
{
    __shared__ float sWq[4096], sWk[4096], sWv[4096];
    __shared__ float sb[192];
    for (int i = threadIdx.x; i < 4096; i += 256) {
        sWq[i] = Wq[i]; sWk[i] = Wk[i]; sWv[i] = Wv[i];
    }
    if (threadIdx.x < 64)       sb[threadIdx.x] = bq[threadIdx.x];
    else if (threadIdx.x < 128) sb[threadIdx.x] = bk[threadIdx.x - 64];
    else if (threadIdx.x < 192) sb[threadIdx.x] = bv[threadIdx.x - 128];
    __syncthreads();

    const int wid  = threadIdx.x >> 6;
    const int lane = threadIdx.x & 63;

    for (int r0 = blockIdx.x * 8; r0 < E_N; r0 += gridDim.x * 8) {
        int ra = r0 + wid * 2;
        int rb = ra + 1;
        bool va = ra < E_N, vb = rb < E_N;
        float xa = va ? x[(long long)ra * 64 + lane] : 0.0f;
        float xb = vb ? x[(long long)rb * 64 + lane] : 0.0f;

        float aq0 = sb[lane], ak0 = sb[64 + lane], av0 = sb[128 + lane];
        float aq1 = aq0, ak1 = ak0, av1 = av0;
        #pragma unroll
        for (int i = 0; i < 64; i++) {
            float xi0 = __shfl(xa, i, 64);
            float xi1 = __shfl(xb, i, 64);
            float wq = sWq[i * 64 + lane];
            float wk = sWk[i * 64 + lane];
            float wv = sWv[i * 64 + lane];
            aq0 += xi0 * wq;  aq1 += xi1 * wq;
            ak0 += xi0 * wk;  ak1 += xi1 * wk;
            av0 += xi0 * wv;  av1 += xi1 * wv;
        }
        if (va) {
            q[(long long)ra * 64 + lane] = aq0;
            k[(long long)ra * 64 + lane] = ak0;
            v[(long long)ra * 64 + lane] = av0;
        }
        if (vb) {
            q[(long long)rb * 64 + lane] = aq1;
            k[(long long)rb * 64 + lane] = ak1;
            v[(long long)rb * 64 + lane] = av1;
        }
    }
}

// ---------------------------------------------------------------------------
// Counting sort by dst: histogram -> 2-level exclusive scan -> scatter
// ---------------------------------------------------------------------------
__global__ __launch_bounds__(256) void hist_kernel(
    const int* __restrict__ e2e, int* __restrict__ counts)
{
    int m = blockIdx.x * 256 + threadIdx.x;
    if (m < M_N) atomicAdd(&counts[e2e[M_N + m]], 1);
}

__global__ __launch_bounds__(256) void scan1_kernel(
    const int* __restrict__ counts, int* __restrict__ cursor,
    int* __restrict__ blocksums)
{
    __shared__ int s[256];
    const int t = threadIdx.x;
    const int base = blockIdx.x * SCAN_CHUNK + t * 8;

    int vals[8];
    int tot = 0;
    #pragma unroll
    for (int j = 0; j < 8; j++) {
        int idx = base + j;
        vals[j] = (idx < E_N) ? counts[idx] : 0;
        tot += vals[j];
    }
    s[t] = tot;
    __syncthreads();
    for (int off = 1; off < 256; off <<= 1) {
        int add = (t >= off) ? s[t - off] : 0;
        __syncthreads();
        s[t] += add;
        __syncthreads();
    }
    int excl = (t == 0) ? 0 : s[t - 1];
    if (t == 255) blocksums[blockIdx.x] = s[255];

    int run = excl;
    #pragma unroll
    for (int j = 0; j < 8; j++) {
        int idx = base + j;
        if (idx < E_N) cursor[idx] = run;
        run += vals[j];
    }
}

__global__ __launch_bounds__(128) void scan2_kernel(
    const int* __restrict__ blocksums, int* __restrict__ blockoff)
{
    __shared__ int s[128];
    const int t = threadIdx.x;
    s[t] = (t < NB1) ? blocksums[t] : 0;
    __syncthreads();
    for (int off = 1; off < 128; off <<= 1) {
        int add = (t >= off) ? s[t - off] : 0;
        __syncthreads();
        s[t] += add;
        __syncthreads();
    }
    if (t < NB1) blockoff[t] = (t == 0) ? 0 : s[t - 1];
}

// scatter: global pos = local cursor + chunk offset (scan3 folded in here)
__global__ __launch_bounds__(256) void scatter_kernel(
    const int* __restrict__ e2e, int* __restrict__ cursor,
    const int* __restrict__ blockoff, int2* __restrict__ sorted)
{
    int m = blockIdx.x * 256 + threadIdx.x;
    if (m < M_N) {
        int src = e2e[m];
        int dst = e2e[M_N + m];
        int pos = atomicAdd(&cursor[dst], 1) + blockoff[dst >> 11];
        sorted[pos] = make_int2(src, m);
    }
}

// ---------------------------------------------------------------------------
// aggregate: one wave per dst edge, 8 pairs processed in parallel per batch.
// Lane = ps*8 + t for the dot phase (pair slot ps, head t): full head-dot
// in-register (no cross-lane reduce). Lane = h*8 + d for accumulation.
// q row read from qmsg (=d_out), msg written back to the same row. No atomics.
// ---------------------------------------------------------------------------
__global__ __launch_bounds__(256) void aggregate_kernel(
    const float* __restrict__ k, const float* __restrict__ v,
    const float* __restrict__ bias,
    const int* __restrict__ counts, const int* __restrict__ cursor,
    const int* __restrict__ blockoff,
    const int2* __restrict__ sorted,
    float* __restrict__ qmsg)
{
    const int wid  = threadIdx.x >> 6;
    const int lane = threadIdx.x & 63;
    const int ps   = lane >> 3;   // pair slot (dot phase) == head h (accum phase)
    const int t    = lane & 7;    // head (dot phase)       == dim d (accum phase)

    for (int e = blockIdx.x * 4 + wid; e < E_N; e += gridDim.x * 4) {
        float qv = qmsg[(long long)e * 64 + lane];

        // broadcast q slice for head t into registers: qs[j] = q[e][t*8+j]
        float qs[8];
        #pragma unroll
        for (int j = 0; j < 8; j++) qs[j] = __shfl(qv, t * 8 + j, 64);

        int end   = cursor[e] + blockoff[e >> 11];
        int cnt   = counts[e];
        int start = end - cnt;

        float acc = 0.0f, wsum = 0.0f;
        for (int i = start; i < end; i += 8) {
            int idx = i + ps;
            bool valid = idx < end;
            int2 p = make_int2(0, 0);
            if (valid) p = sorted[idx];

            const float4* kp = (const float4*)(k + (long long)p.x * 64 + t * 8);
            float4 ka = kp[0], kb = kp[1];
            float bs = bias[(long long)p.y * 8 + t];

            float dot = qs[0] * ka.x + qs[1] * ka.y + qs[2] * ka.z + qs[3] * ka.w
                      + qs[4] * kb.x + qs[5] * kb.y + qs[6] * kb.z + qs[7] * kb.w;
            float w = valid ? __expf(dot * 0.35355339059327373f + bs) : 0.0f;

            // cross-lane broadcast via bpermute (register-based, no LDS hazards)
            int   srcj[8];
            float wj[8];
            #pragma unroll
            for (int j = 0; j < 8; j++) {
                srcj[j] = __shfl(p.x, j * 8, 64);        // pair j's src
                wj[j]   = __shfl(w, j * 8 + ps, 64);     // w[pair j, head h=ps]
            }
            #pragma unroll
            for (int j = 0; j < 8; j++) {
                float vv = v[(long long)srcj[j] * 64 + lane];
                acc  += wj[j] * vv;
                wsum += wj[j];
            }
        }
        qmsg[(long long)e * 64 + lane] = acc / (wsum + 1e-16f);
    }
}

// ---------------------------------------------------------------------------
// out = msg @ Wo + bo, in-place on d_out
// ---------------------------------------------------------------------------
__global__ __launch_bounds__(256) void out_kernel(
    const float* __restrict__ Wo, const float* __restrict__ bo,
    float* __restrict__ out)
{
    __shared__ float sWo[4096];
    __shared__ float sbo[64];
    for (int i = threadIdx.x; i < 4096; i += 256) sWo[i] = Wo[i];
    if (threadIdx.x < 64) sbo[threadIdx.x] = bo[threadIdx.x];
    __syncthreads();

    const int wid  = threadIdx.x >> 6;
    const int lane = threadIdx.x & 63;

    for (int e = blockIdx.x * 4 + wid; e < E_N; e += gridDim.x * 4) {
        float m = out[(long long)e * 64 + lane];
        float o = sbo[lane];
        #pragma unroll
        for (int i = 0; i < 64; i++) {
            o += __shfl(m, i, 64) * sWo[i * 64 + lane];
        }
        out[(long long)e * 64 + lane] = o;
    }
}

extern "C" void kernel_launch(void* const* d_in, const int* in_sizes, int n_in,
                              void* d_out, int out_size, void* d_ws, size_t ws_size,
                              hipStream_t stream) {
    const float* x    = (const float*)d_in[0];
    const int*   e2e  = (const int*)  d_in[1];
    const float* bias = (const float*)d_in[2];
    const float* Wq   = (const float*)d_in[3];
    const float* bq   = (const float*)d_in[4];
    const float* Wk   = (const float*)d_in[5];
    const float* bk   = (const float*)d_in[6];
    const float* Wv   = (const float*)d_in[7];
    const float* bv   = (const float*)d_in[8];
    const float* Wo   = (const float*)d_in[9];
    const float* bo   = (const float*)d_in[10];
    float* out = (float*)d_out;   // q buffer -> msg buffer -> final out (in place)

    // ws: k[12.8M] | v[12.8M] | counts[200k] | cursor[200k] | bsum[128] | boff[128] | sorted[3.2M int2]
    float* k      = (float*)d_ws;
    float* v      = k + (long long)E_N * 64;
    int*   counts = (int*)(v + (long long)E_N * 64);
    int*   cursor = counts + E_N;
    int*   bsum   = cursor + E_N;
    int*   boff   = bsum + 128;
    int2*  sorted = (int2*)(boff + 128);

    hipMemsetAsync(counts, 0, (size_t)E_N * sizeof(int), stream);

    qkv_kernel<<<768, 256, 0, stream>>>(x, Wq, bq, Wk, bk, Wv, bv, out, k, v);

    int mb = (M_N + 255) / 256;   // 12500
    hist_kernel<<<mb, 256, 0, stream>>>(e2e, counts);
    scan1_kernel<<<NB1, 256, 0, stream>>>(counts, cursor, bsum);
    scan2_kernel<<<1, 128, 0, stream>>>(bsum, boff);
    scatter_kernel<<<mb, 256, 0, stream>>>(e2e, cursor, boff, sorted);

    aggregate_kernel<<<8192, 256, 0, stream>>>(k, v, bias, counts, cursor,
                                               boff, sorted, out);

    out_kernel<<<1024, 256, 0, stream>>>(Wo, bo, out);
}

// Round 4
// 946.944 us; speedup vs baseline: 6.9122x; 1.3563x over previous
//
#include <hip/hip_runtime.h>

#define E_N 200000
#define M_N 3200000
#define SCAN_CHUNK 2048
#define NB1 98          // ceil(E_N / SCAN_CHUNK)

typedef __attribute__((ext_vector_type(8))) short bf16x8;   // MFMA A/B frag (4 VGPRs)
typedef __attribute__((ext_vector_type(4))) float f32x4;    // MFMA C/D frag

// fp32 -> bf16 (round to nearest even), as raw short
__device__ __forceinline__ short f2bf(float f) {
    union { float f; unsigned u; } x; x.f = f;
    unsigned r = x.u + 0x7fffu + ((x.u >> 16) & 1u);
    return (short)(r >> 16);
}

// ---------------------------------------------------------------------------
// qkv via MFMA: q/k/v = x @ W{q,k,v} + b  (bf16 inputs, fp32 accumulate).
// One wave per 16-row stripe; block = 4 waves = 64 rows per iter.
// B-fragments (all of Wq/Wk/Wv) live in registers, loaded once per block.
// A-frag layout: A[m=lane&15][k=quad*8+j]; C/D: row=quad*4+reg, col=lane&15.
// E_N % 64 == 0, so no row bounds checks.
// ---------------------------------------------------------------------------
__global__ __launch_bounds__(256) void qkv_mfma(
    const float* __restrict__ x,
    const float* __restrict__ Wq, const float* __restrict__ bq,
    const float* __restrict__ Wk, const float* __restrict__ bk,
    const float* __restrict__ Wv, const float* __restrict__ bv,
    float* __restrict__ q, float* __restrict__ k, float* __restrict__ v)
{
    const int w    = threadIdx.x >> 6;
    const int lane = threadIdx.x & 63;
    const int quad = lane >> 4;
    const int m    = lane & 15;

    // B frags: [col-tile][k-frag]; element j <-> W[kb*32+quad*8+j][ct*16+m]
    bf16x8 Bq[4][2], Bk[4][2], Bv[4][2];
    float  bqv[4], bkv[4], bvv[4];
    #pragma unroll
    for (int ct = 0; ct < 4; ct++) {
        int cc = ct * 16 + m;
        bqv[ct] = bq[cc]; bkv[ct] = bk[cc]; bvv[ct] = bv[cc];
        #pragma unroll
        for (int kb = 0; kb < 2; kb++) {
            #pragma unroll
            for (int j = 0; j < 8; j++) {
                int kk = kb * 32 + quad * 8 + j;
                Bq[ct][kb][j] = f2bf(Wq[kk * 64 + cc]);
                Bk[ct][kb][j] = f2bf(Wk[kk * 64 + cc]);
                Bv[ct][kb][j] = f2bf(Wv[kk * 64 + cc]);
            }
        }
    }

    for (int row0 = blockIdx.x * 64 + w * 16; row0 < E_N; row0 += gridDim.x * 64) {
        // A frags for this stripe: lane reads row (row0+m), cols kb*32+quad*8 ..+7
        const float* xr = x + (long long)(row0 + m) * 64 + quad * 8;
        bf16x8 A[2];
        #pragma unroll
        for (int kb = 0; kb < 2; kb++) {
            float4 p0 = *(const float4*)(xr + kb * 32);
            float4 p1 = *(const float4*)(xr + kb * 32 + 4);
            A[kb][0] = f2bf(p0.x); A[kb][1] = f2bf(p0.y);
            A[kb][2] = f2bf(p0.z); A[kb][3] = f2bf(p0.w);
            A[kb][4] = f2bf(p1.x); A[kb][5] = f2bf(p1.y);
            A[kb][6] = f2bf(p1.z); A[kb][7] = f2bf(p1.w);
        }

        #pragma unroll
        for (int ct = 0; ct < 4; ct++) {
            f32x4 aq = {bqv[ct], bqv[ct], bqv[ct], bqv[ct]};
            f32x4 ak = {bkv[ct], bkv[ct], bkv[ct], bkv[ct]};
            f32x4 av = {bvv[ct], bvv[ct], bvv[ct], bvv[ct]};
            aq = __builtin_amdgcn_mfma_f32_16x16x32_bf16(A[0], Bq[ct][0], aq, 0, 0, 0);
            aq = __builtin_amdgcn_mfma_f32_16x16x32_bf16(A[1], Bq[ct][1], aq, 0, 0, 0);
            ak = __builtin_amdgcn_mfma_f32_16x16x32_bf16(A[0], Bk[ct][0], ak, 0, 0, 0);
            ak = __builtin_amdgcn_mfma_f32_16x16x32_bf16(A[1], Bk[ct][1], ak, 0, 0, 0);
            av = __builtin_amdgcn_mfma_f32_16x16x32_bf16(A[0], Bv[ct][0], av, 0, 0, 0);
            av = __builtin_amdgcn_mfma_f32_16x16x32_bf16(A[1], Bv[ct][1], av, 0, 0, 0);
            #pragma unroll
            for (int i = 0; i < 4; i++) {
                long long off = (long long)(row0 + quad * 4 + i) * 64 + ct * 16 + m;
                q[off] = aq[i]; k[off] = ak[i]; v[off] = av[i];
            }
        }
    }
}

// ---------------------------------------------------------------------------
// Counting sort by dst: histogram -> 2-level exclusive scan -> scatter
// ---------------------------------------------------------------------------
__global__ __launch_bounds__(256) void hist_kernel(
    const int* __restrict__ e2e, int* __restrict__ counts)
{
    int m = blockIdx.x * 256 + threadIdx.x;
    if (m < M_N) atomicAdd(&counts[e2e[M_N + m]], 1);
}

__global__ __launch_bounds__(256) void scan1_kernel(
    const int* __restrict__ counts, int* __restrict__ cursor,
    int* __restrict__ blocksums)
{
    __shared__ int s[256];
    const int t = threadIdx.x;
    const int base = blockIdx.x * SCAN_CHUNK + t * 8;

    int vals[8];
    int tot = 0;
    #pragma unroll
    for (int j = 0; j < 8; j++) {
        int idx = base + j;
        vals[j] = (idx < E_N) ? counts[idx] : 0;
        tot += vals[j];
    }
    s[t] = tot;
    __syncthreads();
    for (int off = 1; off < 256; off <<= 1) {
        int add = (t >= off) ? s[t - off] : 0;
        __syncthreads();
        s[t] += add;
        __syncthreads();
    }
    int excl = (t == 0) ? 0 : s[t - 1];
    if (t == 255) blocksums[blockIdx.x] = s[255];

    int run = excl;
    #pragma unroll
    for (int j = 0; j < 8; j++) {
        int idx = base + j;
        if (idx < E_N) cursor[idx] = run;
        run += vals[j];
    }
}

__global__ __launch_bounds__(128) void scan2_kernel(
    const int* __restrict__ blocksums, int* __restrict__ blockoff)
{
    __shared__ int s[128];
    const int t = threadIdx.x;
    s[t] = (t < NB1) ? blocksums[t] : 0;
    __syncthreads();
    for (int off = 1; off < 128; off <<= 1) {
        int add = (t >= off) ? s[t - off] : 0;
        __syncthreads();
        s[t] += add;
        __syncthreads();
    }
    if (t < NB1) blockoff[t] = (t == 0) ? 0 : s[t - 1];
}

// scatter: global pos = local cursor + chunk offset
__global__ __launch_bounds__(256) void scatter_kernel(
    const int* __restrict__ e2e, int* __restrict__ cursor,
    const int* __restrict__ blockoff, int2* __restrict__ sorted)
{
    int m = blockIdx.x * 256 + threadIdx.x;
    if (m < M_N) {
        int src = e2e[m];
        int dst = e2e[M_N + m];
        int pos = atomicAdd(&cursor[dst], 1) + blockoff[dst >> 11];
        sorted[pos] = make_int2(src, m);
    }
}

// ---------------------------------------------------------------------------
// aggregate: one wave per dst edge, 8 pairs in parallel per batch.
// Dot phase: lane = ps*8 + t (pair slot, head); accum phase: lane = h*8 + d.
// q read from qmsg (=d_out), msg written back to the same row. No atomics.
// ---------------------------------------------------------------------------
__global__ __launch_bounds__(256) void aggregate_kernel(
    const float* __restrict__ k, const float* __restrict__ v,
    const float* __restrict__ bias,
    const int* __restrict__ counts, const int* __restrict__ cursor,
    const int* __restrict__ blockoff,
    const int2* __restrict__ sorted,
    float* __restrict__ qmsg)
{
    const int wid  = threadIdx.x >> 6;
    const int lane = threadIdx.x & 63;
    const int ps   = lane >> 3;
    const int t    = lane & 7;

    for (int e = blockIdx.x * 4 + wid; e < E_N; e += gridDim.x * 4) {
        float qv = qmsg[(long long)e * 64 + lane];

        float qs[8];
        #pragma unroll
        for (int j = 0; j < 8; j++) qs[j] = __shfl(qv, t * 8 + j, 64);

        int end   = cursor[e] + blockoff[e >> 11];
        int cnt   = counts[e];
        int start = end - cnt;

        float acc = 0.0f, wsum = 0.0f;
        for (int i = start; i < end; i += 8) {
            int idx = i + ps;
            bool valid = idx < end;
            int2 p = make_int2(0, 0);
            if (valid) p = sorted[idx];

            const float4* kp = (const float4*)(k + (long long)p.x * 64 + t * 8);
            float4 ka = kp[0], kb = kp[1];
            float bs = bias[(long long)p.y * 8 + t];

            float dot = qs[0] * ka.x + qs[1] * ka.y + qs[2] * ka.z + qs[3] * ka.w
                      + qs[4] * kb.x + qs[5] * kb.y + qs[6] * kb.z + qs[7] * kb.w;
            float w = valid ? __expf(dot * 0.35355339059327373f + bs) : 0.0f;

            int   srcj[8];
            float wj[8];
            #pragma unroll
            for (int j = 0; j < 8; j++) {
                srcj[j] = __shfl(p.x, j * 8, 64);
                wj[j]   = __shfl(w, j * 8 + ps, 64);
            }
            #pragma unroll
            for (int j = 0; j < 8; j++) {
                float vv = v[(long long)srcj[j] * 64 + lane];
                acc  += wj[j] * vv;
                wsum += wj[j];
            }
        }
        qmsg[(long long)e * 64 + lane] = acc / (wsum + 1e-16f);
    }
}

// ---------------------------------------------------------------------------
// out = msg @ Wo + bo via MFMA, in-place on d_out. Same layout as qkv_mfma.
// Each wave fully reads its 16 rows (A frags) before storing the same rows.
// ---------------------------------------------------------------------------
__global__ __launch_bounds__(256) void out_mfma(
    const float* __restrict__ Wo, const float* __restrict__ bo,
    float* __restrict__ out)
{
    const int w    = threadIdx.x >> 6;
    const int lane = threadIdx.x & 63;
    const int quad = lane >> 4;
    const int m    = lane & 15;

    bf16x8 B[4][2];
    float  bov[4];
    #pragma unroll
    for (int ct = 0; ct < 4; ct++) {
        int cc = ct * 16 + m;
        bov[ct] = bo[cc];
        #pragma unroll
        for (int kb = 0; kb < 2; kb++) {
            #pragma unroll
            for (int j = 0; j < 8; j++) {
                int kk = kb * 32 + quad * 8 + j;
                B[ct][kb][j] = f2bf(Wo[kk * 64 + cc]);
            }
        }
    }

    for (int row0 = blockIdx.x * 64 + w * 16; row0 < E_N; row0 += gridDim.x * 64) {
        const float* xr = out + (long long)(row0 + m) * 64 + quad * 8;
        bf16x8 A[2];
        #pragma unroll
        for (int kb = 0; kb < 2; kb++) {
            float4 p0 = *(const float4*)(xr + kb * 32);
            float4 p1 = *(const float4*)(xr + kb * 32 + 4);
            A[kb][0] = f2bf(p0.x); A[kb][1] = f2bf(p0.y);
            A[kb][2] = f2bf(p0.z); A[kb][3] = f2bf(p0.w);
            A[kb][4] = f2bf(p1.x); A[kb][5] = f2bf(p1.y);
            A[kb][6] = f2bf(p1.z); A[kb][7] = f2bf(p1.w);
        }

        f32x4 acc[4];
        #pragma unroll
        for (int ct = 0; ct < 4; ct++) {
            acc[ct] = (f32x4){bov[ct], bov[ct], bov[ct], bov[ct]};
            acc[ct] = __builtin_amdgcn_mfma_f32_16x16x32_bf16(A[0], B[ct][0], acc[ct], 0, 0, 0);
            acc[ct] = __builtin_amdgcn_mfma_f32_16x16x32_bf16(A[1], B[ct][1], acc[ct], 0, 0, 0);
        }
        #pragma unroll
        for (int ct = 0; ct < 4; ct++) {
            #pragma unroll
            for (int i = 0; i < 4; i++) {
                out[(long long)(row0 + quad * 4 + i) * 64 + ct * 16 + m] = acc[ct][i];
            }
        }
    }
}

extern "C" void kernel_launch(void* const* d_in, const int* in_sizes, int n_in,
                              void* d_out, int out_size, void* d_ws, size_t ws_size,
                              hipStream_t stream) {
    const float* x    = (const float*)d_in[0];
    const int*   e2e  = (const int*)  d_in[1];
    const float* bias = (const float*)d_in[2];
    const float* Wq   = (const float*)d_in[3];
    const float* bq   = (const float*)d_in[4];
    const float* Wk   = (const float*)d_in[5];
    const float* bk   = (const float*)d_in[6];
    const float* Wv   = (const float*)d_in[7];
    const float* bv   = (const float*)d_in[8];
    const float* Wo   = (const float*)d_in[9];
    const float* bo   = (const float*)d_in[10];
    float* out = (float*)d_out;   // q buffer -> msg buffer -> final out (in place)

    // ws: k[12.8M] | v[12.8M] | counts[200k] | cursor[200k] | bsum[128] | boff[128] | sorted[3.2M int2]
    float* k      = (float*)d_ws;
    float* v      = k + (long long)E_N * 64;
    int*   counts = (int*)(v + (long long)E_N * 64);
    int*   cursor = counts + E_N;
    int*   bsum   = cursor + E_N;
    int*   boff   = bsum + 128;
    int2*  sorted = (int2*)(boff + 128);

    hipMemsetAsync(counts, 0, (size_t)E_N * sizeof(int), stream);

    qkv_mfma<<<640, 256, 0, stream>>>(x, Wq, bq, Wk, bk, Wv, bv, out, k, v);

    int mb = (M_N + 255) / 256;   // 12500
    hist_kernel<<<mb, 256, 0, stream>>>(e2e, counts);
    scan1_kernel<<<NB1, 256, 0, stream>>>(counts, cursor, bsum);
    scan2_kernel<<<1, 128, 0, stream>>>(bsum, boff);
    scatter_kernel<<<mb, 256, 0, stream>>>(e2e, cursor, boff, sorted);

    aggregate_kernel<<<8192, 256, 0, stream>>>(k, v, bias, counts, cursor,
                                               boff, sorted, out);

    out_mfma<<<640, 256, 0, stream>>>(Wo, bo, out);
}

// Round 5
// 719.562 us; speedup vs baseline: 9.0964x; 1.3160x over previous
//
#include <hip/hip_runtime.h>

#define E_N 200000
#define M_N 3200000
#define SCAN_CHUNK 2048
#define NB1 98          // ceil(E_N / SCAN_CHUNK)

typedef __attribute__((ext_vector_type(8))) short bf16x8;      // MFMA A/B frag
typedef __attribute__((ext_vector_type(4))) float f32x4;       // MFMA C/D frag
typedef __attribute__((ext_vector_type(8))) _Float16 f16x8;    // 16B of f16

// fp32 -> bf16 (round to nearest even), raw short
__device__ __forceinline__ short f2bf(float f) {
    union { float f; unsigned u; } x; x.f = f;
    unsigned r = x.u + 0x7fffu + ((x.u >> 16) & 1u);
    return (short)(r >> 16);
}

// ---------------------------------------------------------------------------
// qkv via MFMA: q (fp32, to d_out) and k/v (f16) = x @ W + b.
// One wave per 16-row stripe; block = 4 waves = 64 rows/iter. E_N % 64 == 0.
// ---------------------------------------------------------------------------
__global__ __launch_bounds__(256) void qkv_mfma(
    const float* __restrict__ x,
    const float* __restrict__ Wq, const float* __restrict__ bq,
    const float* __restrict__ Wk, const float* __restrict__ bk,
    const float* __restrict__ Wv, const float* __restrict__ bv,
    float* __restrict__ q, _Float16* __restrict__ k, _Float16* __restrict__ v)
{
    const int w    = threadIdx.x >> 6;
    const int lane = threadIdx.x & 63;
    const int quad = lane >> 4;
    const int m    = lane & 15;

    bf16x8 Bq[4][2], Bk[4][2], Bv[4][2];
    float  bqv[4], bkv[4], bvv[4];
    #pragma unroll
    for (int ct = 0; ct < 4; ct++) {
        int cc = ct * 16 + m;
        bqv[ct] = bq[cc]; bkv[ct] = bk[cc]; bvv[ct] = bv[cc];
        #pragma unroll
        for (int kb = 0; kb < 2; kb++) {
            #pragma unroll
            for (int j = 0; j < 8; j++) {
                int kk = kb * 32 + quad * 8 + j;
                Bq[ct][kb][j] = f2bf(Wq[kk * 64 + cc]);
                Bk[ct][kb][j] = f2bf(Wk[kk * 64 + cc]);
                Bv[ct][kb][j] = f2bf(Wv[kk * 64 + cc]);
            }
        }
    }

    for (int row0 = blockIdx.x * 64 + w * 16; row0 < E_N; row0 += gridDim.x * 64) {
        const float* xr = x + (long long)(row0 + m) * 64 + quad * 8;
        bf16x8 A[2];
        #pragma unroll
        for (int kb = 0; kb < 2; kb++) {
            float4 p0 = *(const float4*)(xr + kb * 32);
            float4 p1 = *(const float4*)(xr + kb * 32 + 4);
            A[kb][0] = f2bf(p0.x); A[kb][1] = f2bf(p0.y);
            A[kb][2] = f2bf(p0.z); A[kb][3] = f2bf(p0.w);
            A[kb][4] = f2bf(p1.x); A[kb][5] = f2bf(p1.y);
            A[kb][6] = f2bf(p1.z); A[kb][7] = f2bf(p1.w);
        }

        #pragma unroll
        for (int ct = 0; ct < 4; ct++) {
            f32x4 aq = {bqv[ct], bqv[ct], bqv[ct], bqv[ct]};
            f32x4 ak = {bkv[ct], bkv[ct], bkv[ct], bkv[ct]};
            f32x4 av = {bvv[ct], bvv[ct], bvv[ct], bvv[ct]};
            aq = __builtin_amdgcn_mfma_f32_16x16x32_bf16(A[0], Bq[ct][0], aq, 0, 0, 0);
            aq = __builtin_amdgcn_mfma_f32_16x16x32_bf16(A[1], Bq[ct][1], aq, 0, 0, 0);
            ak = __builtin_amdgcn_mfma_f32_16x16x32_bf16(A[0], Bk[ct][0], ak, 0, 0, 0);
            ak = __builtin_amdgcn_mfma_f32_16x16x32_bf16(A[1], Bk[ct][1], ak, 0, 0, 0);
            av = __builtin_amdgcn_mfma_f32_16x16x32_bf16(A[0], Bv[ct][0], av, 0, 0, 0);
            av = __builtin_amdgcn_mfma_f32_16x16x32_bf16(A[1], Bv[ct][1], av, 0, 0, 0);
            #pragma unroll
            for (int i = 0; i < 4; i++) {
                long long off = (long long)(row0 + quad * 4 + i) * 64 + ct * 16 + m;
                q[off] = aq[i];
                k[off] = (_Float16)ak[i];
                v[off] = (_Float16)av[i];
            }
        }
    }
}

// ---------------------------------------------------------------------------
// Counting sort by dst: histogram -> 2-level exclusive scan -> scatter
// ---------------------------------------------------------------------------
__global__ __launch_bounds__(256) void hist_kernel(
    const int* __restrict__ e2e, int* __restrict__ counts)
{
    int m4 = (blockIdx.x * 256 + threadIdx.x) * 4;
    if (m4 < M_N) {
        int4 d = *(const int4*)(e2e + M_N + m4);
        atomicAdd(&counts[d.x], 1);
        atomicAdd(&counts[d.y], 1);
        atomicAdd(&counts[d.z], 1);
        atomicAdd(&counts[d.w], 1);
    }
}

__global__ __launch_bounds__(256) void scan1_kernel(
    const int* __restrict__ counts, int* __restrict__ cursor,
    int* __restrict__ blocksums)
{
    __shared__ int s[256];
    const int t = threadIdx.x;
    const int base = blockIdx.x * SCAN_CHUNK + t * 8;

    int vals[8];
    int tot = 0;
    #pragma unroll
    for (int j = 0; j < 8; j++) {
        int idx = base + j;
        vals[j] = (idx < E_N) ? counts[idx] : 0;
        tot += vals[j];
    }
    s[t] = tot;
    __syncthreads();
    for (int off = 1; off < 256; off <<= 1) {
        int add = (t >= off) ? s[t - off] : 0;
        __syncthreads();
        s[t] += add;
        __syncthreads();
    }
    int excl = (t == 0) ? 0 : s[t - 1];
    if (t == 255) blocksums[blockIdx.x] = s[255];

    int run = excl;
    #pragma unroll
    for (int j = 0; j < 8; j++) {
        int idx = base + j;
        if (idx < E_N) cursor[idx] = run;
        run += vals[j];
    }
}

__global__ __launch_bounds__(128) void scan2_kernel(
    const int* __restrict__ blocksums, int* __restrict__ blockoff)
{
    __shared__ int s[128];
    const int t = threadIdx.x;
    s[t] = (t < NB1) ? blocksums[t] : 0;
    __syncthreads();
    for (int off = 1; off < 128; off <<= 1) {
        int add = (t >= off) ? s[t - off] : 0;
        __syncthreads();
        s[t] += add;
        __syncthreads();
    }
    if (t < NB1) blockoff[t] = (t == 0) ? 0 : s[t - 1];
}

// scatter: place src into sorted order AND permute bias into sorted order (f16)
__global__ __launch_bounds__(256) void scatter_kernel(
    const int* __restrict__ e2e, const float* __restrict__ bias,
    int* __restrict__ cursor, const int* __restrict__ blockoff,
    int* __restrict__ sorted, _Float16* __restrict__ bias_s)
{
    int m = blockIdx.x * 256 + threadIdx.x;
    if (m < M_N) {
        int src = e2e[m];
        int dst = e2e[M_N + m];
        int pos = atomicAdd(&cursor[dst], 1) + blockoff[dst >> 11];
        sorted[pos] = src;

        float4 b0 = *(const float4*)(bias + (long long)m * 8);
        float4 b1 = *(const float4*)(bias + (long long)m * 8 + 4);
        f16x8 bb;
        bb[0] = (_Float16)b0.x; bb[1] = (_Float16)b0.y;
        bb[2] = (_Float16)b0.z; bb[3] = (_Float16)b0.w;
        bb[4] = (_Float16)b1.x; bb[5] = (_Float16)b1.y;
        bb[6] = (_Float16)b1.z; bb[7] = (_Float16)b1.w;
        *(f16x8*)(bias_s + (long long)pos * 8) = bb;
    }
}

// ---------------------------------------------------------------------------
// aggregate: one wave per dst edge, 8 pairs in parallel per batch.
// Dot phase: lane = ps*8 + t (pair slot, head); accum phase: lane = h*8 + d.
// k/v/bias_s in f16; q from qmsg (=d_out), msg written back in place.
// ---------------------------------------------------------------------------
__global__ __launch_bounds__(256) void aggregate_kernel(
    const _Float16* __restrict__ k, const _Float16* __restrict__ v,
    const _Float16* __restrict__ bias_s,
    const int* __restrict__ counts, const int* __restrict__ cursor,
    const int* __restrict__ blockoff,
    const int* __restrict__ sorted,
    float* __restrict__ qmsg)
{
    const int wid  = threadIdx.x >> 6;
    const int lane = threadIdx.x & 63;
    const int ps   = lane >> 3;
    const int t    = lane & 7;

    for (int e = blockIdx.x * 4 + wid; e < E_N; e += gridDim.x * 4) {
        float qv = qmsg[(long long)e * 64 + lane];

        float qs[8];
        #pragma unroll
        for (int j = 0; j < 8; j++) qs[j] = __shfl(qv, t * 8 + j, 64);

        int end   = cursor[e] + blockoff[e >> 11];
        int cnt   = counts[e];
        int start = end - cnt;

        float acc = 0.0f, wsum = 0.0f;
        for (int i = start; i < end; i += 8) {
            int idx = i + ps;
            bool valid = idx < end;
            int src = valid ? sorted[idx] : 0;
            float bs = valid ? (float)bias_s[(long long)idx * 8 + t] : 0.0f;

            f16x8 kk = *(const f16x8*)(k + (long long)src * 64 + t * 8);
            float dot = 0.0f;
            #pragma unroll
            for (int j = 0; j < 8; j++) dot = fmaf(qs[j], (float)kk[j], dot);

            float w = valid ? __expf(fmaf(dot, 0.35355339059327373f, bs)) : 0.0f;

            int   srcj[8];
            float wj[8];
            #pragma unroll
            for (int j = 0; j < 8; j++) {
                srcj[j] = __shfl(src, j * 8, 64);
                wj[j]   = __shfl(w, j * 8 + ps, 64);
            }
            #pragma unroll
            for (int j = 0; j < 8; j++) {
                float vv = (float)v[(long long)srcj[j] * 64 + lane];
                acc  += wj[j] * vv;
                wsum += wj[j];
            }
        }
        qmsg[(long long)e * 64 + lane] = acc / (wsum + 1e-16f);
    }
}

// ---------------------------------------------------------------------------
// out = msg @ Wo + bo via MFMA, in-place on d_out.
// ---------------------------------------------------------------------------
__global__ __launch_bounds__(256) void out_mfma(
    const float* __restrict__ Wo, const float* __restrict__ bo,
    float* __restrict__ out)
{
    const int w    = threadIdx.x >> 6;
    const int lane = threadIdx.x & 63;
    const int quad = lane >> 4;
    const int m    = lane & 15;

    bf16x8 B[4][2];
    float  bov[4];
    #pragma unroll
    for (int ct = 0; ct < 4; ct++) {
        int cc = ct * 16 + m;
        bov[ct] = bo[cc];
        #pragma unroll
        for (int kb = 0; kb < 2; kb++) {
            #pragma unroll
            for (int j = 0; j < 8; j++) {
                int kk = kb * 32 + quad * 8 + j;
                B[ct][kb][j] = f2bf(Wo[kk * 64 + cc]);
            }
        }
    }

    for (int row0 = blockIdx.x * 64 + w * 16; row0 < E_N; row0 += gridDim.x * 64) {
        const float* xr = out + (long long)(row0 + m) * 64 + quad * 8;
        bf16x8 A[2];
        #pragma unroll
        for (int kb = 0; kb < 2; kb++) {
            float4 p0 = *(const float4*)(xr + kb * 32);
            float4 p1 = *(const float4*)(xr + kb * 32 + 4);
            A[kb][0] = f2bf(p0.x); A[kb][1] = f2bf(p0.y);
            A[kb][2] = f2bf(p0.z); A[kb][3] = f2bf(p0.w);
            A[kb][4] = f2bf(p1.x); A[kb][5] = f2bf(p1.y);
            A[kb][6] = f2bf(p1.z); A[kb][7] = f2bf(p1.w);
        }

        f32x4 acc[4];
        #pragma unroll
        for (int ct = 0; ct < 4; ct++) {
            acc[ct] = (f32x4){bov[ct], bov[ct], bov[ct], bov[ct]};
            acc[ct] = __builtin_amdgcn_mfma_f32_16x16x32_bf16(A[0], B[ct][0], acc[ct], 0, 0, 0);
            acc[ct] = __builtin_amdgcn_mfma_f32_16x16x32_bf16(A[1], B[ct][1], acc[ct], 0, 0, 0);
        }
        #pragma unroll
        for (int ct = 0; ct < 4; ct++) {
            #pragma unroll
            for (int i = 0; i < 4; i++) {
                out[(long long)(row0 + quad * 4 + i) * 64 + ct * 16 + m] = acc[ct][i];
            }
        }
    }
}

extern "C" void kernel_launch(void* const* d_in, const int* in_sizes, int n_in,
                              void* d_out, int out_size, void* d_ws, size_t ws_size,
                              hipStream_t stream) {
    const float* x    = (const float*)d_in[0];
    const int*   e2e  = (const int*)  d_in[1];
    const float* bias = (const float*)d_in[2];
    const float* Wq   = (const float*)d_in[3];
    const float* bq   = (const float*)d_in[4];
    const float* Wk   = (const float*)d_in[5];
    const float* bk   = (const float*)d_in[6];
    const float* Wv   = (const float*)d_in[7];
    const float* bv   = (const float*)d_in[8];
    const float* Wo   = (const float*)d_in[9];
    const float* bo   = (const float*)d_in[10];
    float* out = (float*)d_out;   // q buffer -> msg buffer -> final out (in place)

    // ws: k_h[12.8M f16] | v_h[12.8M f16] | counts | cursor | bsum | boff |
    //     sorted[3.2M int] | bias_s[25.6M f16]   (total ~117 MB)
    _Float16* kh     = (_Float16*)d_ws;
    _Float16* vh     = kh + (long long)E_N * 64;
    int*      counts = (int*)(vh + (long long)E_N * 64);
    int*      cursor = counts + E_N;
    int*      bsum   = cursor + E_N;
    int*      boff   = bsum + 128;
    int*      sorted = boff + 128;
    _Float16* bias_s = (_Float16*)(sorted + M_N);

    hipMemsetAsync(counts, 0, (size_t)E_N * sizeof(int), stream);

    qkv_mfma<<<640, 256, 0, stream>>>(x, Wq, bq, Wk, bk, Wv, bv, out, kh, vh);

    hist_kernel<<<M_N / 1024, 256, 0, stream>>>(e2e, counts);
    scan1_kernel<<<NB1, 256, 0, stream>>>(counts, cursor, bsum);
    scan2_kernel<<<1, 128, 0, stream>>>(bsum, boff);
    scatter_kernel<<<(M_N + 255) / 256, 256, 0, stream>>>(e2e, bias, cursor,
                                                          boff, sorted, bias_s);

    aggregate_kernel<<<8192, 256, 0, stream>>>(kh, vh, bias_s, counts, cursor,
                                               boff, sorted, out);

    out_mfma<<<640, 256, 0, stream>>>(Wo, bo, out);
}